// Round 5
// baseline (2441.804 us; speedup 1.0000x reference)
//
#include <hip/hip_runtime.h>

// RNNSequenceClassifier on MI355X.
// R5: inputs are FLOAT32 (proven by R4 dtype probe: bf16-reads NaN'd, adaptive f32 reads clean);
//     output is FLOAT32 (R4's absmax 1.109 == f32-view aliasing of bf16-written p region).
// Adaptive readers + tripwires retained this round as insurance; strip after PASS.

typedef unsigned short ushort_t;
typedef __bf16 bf16x8 __attribute__((ext_vector_type(8)));
typedef float f32x4 __attribute__((ext_vector_type(4)));

#define NENT 200000
#define NVOC 50000
#define NREL 500
#define KPAD 512

__device__ __forceinline__ float b2f(ushort_t u) {
    return __uint_as_float(((unsigned)u) << 16);
}
__device__ __forceinline__ ushort_t f2b(float f) {
    unsigned u = __float_as_uint(f);
    unsigned r = (u + 0x7FFFu + ((u >> 16) & 1u)) >> 16;
    return (ushort_t)r;
}
__device__ __forceinline__ float sigm(float x) { return 1.f / (1.f + __expf(-x)); }

// adaptive float read: bf16 (df==0) or f32 (df==1)
__device__ __forceinline__ float acc_f(const void* p, long long i, int df) {
    return df ? ((const float*)p)[i] : b2f(((const ushort_t*)p)[i]);
}
// adaptive int read: int32 (di==0) or int64-low-word (di==1)
__device__ __forceinline__ int iacc(const void* p, long long i, int di) {
    return di ? ((const int*)p)[2 * i] : ((const int*)p)[i];
}
__device__ __forceinline__ int isbad(float v) {
    return (v != v) || (fabsf(v) > 1e4f);
}

// ---------------- sentinel (f32 out) ------------------------------------------------
__global__ void k_sentinel(float* __restrict__ out, int n, float val) {
    int i = blockIdx.x * 256 + threadIdx.x;
    if (i < n) out[i] = val;
}

// ---------------- dtype detect + flag init ------------------------------------------
__global__ void k_detect(const void* wordE, const void* triples,
                         unsigned* __restrict__ flags, unsigned* __restrict__ dflag) {
    __shared__ int cnt[2];
    int tid = threadIdx.x;
    if (tid < 2) cnt[tid] = 0;
    __syncthreads();
    const ushort_t* w = (const ushort_t*)wordE;
    int local = 0;
    for (int i = tid; i < 1000000; i += 256) {
        ushort_t u = w[i];
        float v = b2f(u);
        if (((u >> 7) & 0xFF) == 0xFF || fabsf(v) > 1e3f) local++;
    }
    if (local) atomicAdd(&cnt[0], local);
    const int* t32 = (const int*)triples;
    int nz = 0;
    for (int i = tid; i < 1500; i += 256) {
        if (t32[2 * i + 1] != 0) nz++;
    }
    if (nz) atomicAdd(&cnt[1], nz);
    __syncthreads();
    if (tid == 0) {
        unsigned df = 0;
        if (cnt[0] > 0) df |= 1u;  // floats are f32
        if (cnt[1] == 0) df |= 2u; // ints are i64
        *dflag = df;
        *flags = 0;
    }
}

// ---------------- tripwires ----------------------------------------------------------
__global__ void k_check_in(const void* p, long long n, unsigned bit,
                           const unsigned* __restrict__ dflag, unsigned* __restrict__ flags) {
    int df = (*dflag) & 1;
    long long i = (long long)blockIdx.x * 256 + threadIdx.x;
    long long stride = (long long)gridDim.x * 256;
    int bad = 0;
    for (; i < n; i += stride) bad |= isbad(acc_f(p, i, df));
    if (bad) atomicOr(flags, bit);
}
__global__ void k_check_ws(const ushort_t* __restrict__ p, long long n, unsigned bit,
                           unsigned* __restrict__ flags) {
    long long i = (long long)blockIdx.x * 256 + threadIdx.x;
    long long stride = (long long)gridDim.x * 256;
    int bad = 0;
    for (; i < n; i += stride) bad |= isbad(b2f(p[i]));
    if (bad) atomicOr(flags, bit);
}
__global__ void k_check_f32(const float* __restrict__ p, long long n, unsigned bit,
                            unsigned* __restrict__ flags) {
    long long i = (long long)blockIdx.x * 256 + threadIdx.x;
    long long stride = (long long)gridDim.x * 256;
    int bad = 0;
    for (; i < n; i += stride) bad |= isbad(p[i]);
    if (bad) atomicOr(flags, bit);
}

// ---------------- prep: Wb[112][256], trelP[500][112], wihT[512][1024], whhP --------
__global__ void k_prep(const void* __restrict__ Went, const void* __restrict__ wih,
                       const void* __restrict__ whh, const void* __restrict__ relE,
                       ushort_t* __restrict__ Wb, ushort_t* __restrict__ wihT,
                       unsigned* __restrict__ whhP, float* __restrict__ trelP,
                       const unsigned* __restrict__ dflag) {
    int df = (*dflag) & 1;
    int i = blockIdx.x * 256 + threadIdx.x;
    int stride = gridDim.x * 256;
    if (i < 112 * 256) {
        int n = i >> 8, k = i & 255;
        float v = 0.f;
        if (n < 100) {
            if (k < 100) v = acc_f(Went, n * 200 + k, df);
            else if (k >= 128 && k < 228) v = acc_f(Went, n * 200 + 100 + (k - 128), df);
        }
        Wb[i] = f2b(v);
    }
    for (int j = i; j < 500 * 128; j += stride) {
        int r_ = j >> 7, d = j & 127;
        if (d < 112) trelP[r_ * 112 + d] = (d < 100) ? tanhf(acc_f(relE, r_ * 100 + d, df)) : 0.f;
    }
    for (int j = i; j < 512 * 1024; j += stride) {
        int k = j >> 10, n = j & 1023;
        wihT[j] = (k < 500) ? f2b(acc_f(wih, (long long)n * 500 + k, df)) : (ushort_t)0;
    }
    for (int j = i; j < 128 * 1024; j += stride) {
        int k2 = j >> 10, n = j & 1023;
        unsigned lo = f2b(acc_f(whh, n * 256 + 2 * k2, df));
        unsigned hi = f2b(acc_f(whh, n * 256 + 2 * k2 + 1, df));
        whhP[j] = lo | (hi << 16);
    }
}

// ---------------- graph kernel: one block per (b,s), fused transform MFMA -----------
__global__ __launch_bounds__(128) void k_graph(const void* __restrict__ inputs,
                                               const void* __restrict__ triples,
                                               const void* __restrict__ id2,
                                               const void* __restrict__ wordE,
                                               const void* __restrict__ entE,
                                               const ushort_t* __restrict__ Wb,
                                               const float* __restrict__ trelP,
                                               ushort_t* __restrict__ tfeat,
                                               const unsigned* __restrict__ dflag) {
    unsigned dfw = *dflag;
    int df = dfw & 1, di = (dfw >> 1) & 1;
    int bs = blockIdx.x;
    int tid = threadIdx.x;
    __shared__ __align__(16) ushort_t As[32][256];  // [t][k]: head k<100, tail 128..227
    __shared__ int rids[32];
    __shared__ float e_sm[32];
    __shared__ float alpha[32];
    __shared__ int vflag;
    if (tid == 0) vflag = 0;
    __syncthreads();
    int t = tid >> 2, l4 = tid & 3;
    long long base3 = ((long long)bs * 32 + t) * 3;
    int hid = iacc(triples, base3, di);
    int tl = iacc(triples, base3 + 1, di);
    int rid = iacc(triples, base3 + 2, di);
    hid = min(max(hid, 0), NENT - 1);
    tl = min(max(tl, 0), NENT - 1);
    rid = min(max(rid, 0), NREL - 1);
    if (l4 == 0) {
        rids[t] = rid;
        if (iacc(id2, (long long)bs * 32 + t, di) != -1) vflag = 1;
    }
    for (int k = l4; k < 256; k += 4) {
        float v = 0.f;
        if (k < 100) v = acc_f(entE, (long long)hid * 100 + k, df);
        else if (k >= 128 && k < 228) v = acc_f(entE, (long long)tl * 100 + (k - 128), df);
        As[t][k] = f2b(v);
    }
    __syncthreads();
    // GEMM: D[m][n] = sum_k As[m][k]*Wb[n][k], m=32 rows (2 waves x 16), n=112, K=256
    int wave = tid >> 6, lane = tid & 63, m16 = lane & 15, q = lane >> 4;
    f32x4 acc[7];
#pragma unroll
    for (int nt = 0; nt < 7; nt++) acc[nt] = {0.f, 0.f, 0.f, 0.f};
#pragma unroll
    for (int ks = 0; ks < 8; ++ks) {
        bf16x8 af = *reinterpret_cast<const bf16x8*>(&As[wave * 16 + m16][ks * 32 + q * 8]);
#pragma unroll
        for (int nt = 0; nt < 7; ++nt) {
            bf16x8 bf_ = *reinterpret_cast<const bf16x8*>(&Wb[(nt * 16 + m16) * 256 + ks * 32 + q * 8]);
            acc[nt] = __builtin_amdgcn_mfma_f32_16x16x32_bf16(af, bf_, acc[nt], 0, 0, 0);
        }
    }
#pragma unroll
    for (int rr = 0; rr < 4; ++rr) {
        int m = wave * 16 + q * 4 + rr;
        const float* tr = trelP + rids[m] * 112;
        float s = 0.f;
#pragma unroll
        for (int nt = 0; nt < 7; ++nt) s += tanhf(acc[nt][rr]) * tr[nt * 16 + m16];
        s += __shfl_xor(s, 1);
        s += __shfl_xor(s, 2);
        s += __shfl_xor(s, 4);
        s += __shfl_xor(s, 8);
        if (m16 == 0) e_sm[m] = s;
    }
    __syncthreads();
    if (tid < 32) {
        float v = e_sm[tid];
        float mx = v;
        for (int off = 16; off >= 1; off >>= 1) mx = fmaxf(mx, __shfl_xor(mx, off));
        float ex = __expf(v - mx);
        float sm = ex;
        for (int off = 16; off >= 1; off >>= 1) sm += __shfl_xor(sm, off);
        alpha[tid] = ex / sm;
    }
    __syncthreads();
    float scale = vflag ? 1.f : 0.f;
    long long row = (long long)bs * KPAD;
    for (int k = tid; k < 200; k += 128) {
        int kk = (k < 100) ? k : (k + 28);
        float ge = 0.f;
#pragma unroll 8
        for (int tt = 0; tt < 32; ++tt) ge += alpha[tt] * b2f(As[tt][kk]);
        tfeat[row + 300 + k] = f2b(ge * scale);
    }
    int w = iacc(inputs, bs, di);
    w = min(max(w, 0), NVOC - 1);
    for (int j = tid; j < 300; j += 128) tfeat[row + j] = f2b(acc_f(wordE, (long long)w * 300 + j, df));
    if (tid < 12) tfeat[row + 500 + tid] = 0;
}

// ---------------- GEMM: xw = tfeat @ w_ihT + b_ih + b_hh (bf16 out) -----------------
__global__ __launch_bounds__(256) void k_gemm_xw(const ushort_t* __restrict__ A,
                                                 const ushort_t* __restrict__ Bm,
                                                 const void* __restrict__ bih,
                                                 const void* __restrict__ bhh,
                                                 ushort_t* __restrict__ xwB,
                                                 const unsigned* __restrict__ dflag) {
    int df = (*dflag) & 1;
    __shared__ __align__(16) ushort_t As[64 * 32];
    __shared__ __align__(16) ushort_t Bs[64 * 32];
    int tid = threadIdx.x;
    int i0 = blockIdx.x * 64, n0 = blockIdx.y * 64;
    int wave = tid >> 6, lane = tid & 63, m16 = lane & 15, q = lane >> 4;
    f32x4 acc[4];
#pragma unroll
    for (int t = 0; t < 4; t++) acc[t] = {0.f, 0.f, 0.f, 0.f};
    int r = tid >> 2, cq = (tid & 3) * 8;
    int kk = tid >> 3, nn = (tid & 7) * 8;
    for (int kt = 0; kt < 16; ++kt) {
        int k0 = kt * 32;
        {
            const ushort_t* src = A + (i0 + r) * 512 + k0 + cq;
            ushort4 v0 = *(const ushort4*)src;
            ushort4 v1 = *(const ushort4*)(src + 4);
            *(ushort4*)&As[r * 32 + cq] = v0;
            *(ushort4*)&As[r * 32 + cq + 4] = v1;
        }
        {
            const ushort_t* src = Bm + (k0 + kk) * 1024 + n0 + nn;
            ushort4 v0 = *(const ushort4*)(src);
            ushort4 v1 = *(const ushort4*)(src + 4);
            Bs[(nn + 0) * 32 + kk] = v0.x; Bs[(nn + 1) * 32 + kk] = v0.y;
            Bs[(nn + 2) * 32 + kk] = v0.z; Bs[(nn + 3) * 32 + kk] = v0.w;
            Bs[(nn + 4) * 32 + kk] = v1.x; Bs[(nn + 5) * 32 + kk] = v1.y;
            Bs[(nn + 6) * 32 + kk] = v1.z; Bs[(nn + 7) * 32 + kk] = v1.w;
        }
        __syncthreads();
        bf16x8 af = *reinterpret_cast<const bf16x8*>(&As[(wave * 16 + m16) * 32 + q * 8]);
#pragma unroll
        for (int t = 0; t < 4; t++) {
            bf16x8 bf_ = *reinterpret_cast<const bf16x8*>(&Bs[(t * 16 + m16) * 32 + q * 8]);
            acc[t] = __builtin_amdgcn_mfma_f32_16x16x32_bf16(af, bf_, acc[t], 0, 0, 0);
        }
        __syncthreads();
    }
#pragma unroll
    for (int t = 0; t < 4; t++) {
        int n = n0 + t * 16 + m16;
        float bias = acc_f(bih, n, df) + acc_f(bhh, n, df);
#pragma unroll
        for (int rr = 0; rr < 4; rr++) {
            int i = i0 + wave * 16 + q * 4 + rr;
            xwB[i * 1024 + n] = f2b(acc[t][rr] + bias);
        }
    }
}

// ---------------- LSTM scan: 32 blocks x 1024 threads, 2 batch rows per block -------
__global__ __launch_bounds__(1024) void k_lstm(const ushort_t* __restrict__ xwB,
                                               const unsigned* __restrict__ whhP,
                                               const void* __restrict__ lengths,
                                               ushort_t* __restrict__ hallB,
                                               const unsigned* __restrict__ dflag) {
    int di = ((*dflag) >> 1) & 1;
    int b0 = blockIdx.x * 2;
    int n = threadIdx.x;
    __shared__ __align__(16) float hsI[512];
    __shared__ float cs[2][256];
    __shared__ float gl[2][1024];
    if (n < 512) {
        hsI[n] = 0.f;
        cs[n & 1][n >> 1] = 0.f;
    }
    __syncthreads();
    int len0 = iacc(lengths, b0, di), len1 = iacc(lengths, b0 + 1, di);
    const ushort_t* x0 = xwB + (b0 * 128) * 1024 + n;
    const ushort_t* x1 = xwB + ((b0 + 1) * 128) * 1024 + n;
    for (int s = 0; s < 128; ++s) {
        float a0 = b2f(x0[s * 1024]);
        float a1 = b2f(x1[s * 1024]);
#pragma unroll 8
        for (int k2 = 0; k2 < 128; ++k2) {
            unsigned u = whhP[k2 * 1024 + n];
            float w0 = __uint_as_float(u << 16);
            float w1 = __uint_as_float(u & 0xFFFF0000u);
            float4 hv = *(const float4*)&hsI[k2 * 4];
            a0 += hv.x * w0 + hv.z * w1;
            a1 += hv.y * w0 + hv.w * w1;
        }
        gl[0][n] = a0;
        gl[1][n] = a1;
        __syncthreads();
        if (n < 512) {
            int u = n >> 1, j = n & 1;
            float ig = gl[j][u], fg = gl[j][u + 256], gg = gl[j][u + 512], og = gl[j][u + 768];
            float c = sigm(fg) * cs[j][u] + sigm(ig) * tanhf(gg);
            float h = sigm(og) * tanhf(c);
            cs[j][u] = c;
            hsI[u * 2 + j] = h;
            int bb = b0 + j;
            int len = j ? len1 : len0;
            hallB[(bb * 128 + s) * 256 + u] = f2b((s < len) ? h : 0.f);
        }
        __syncthreads();
    }
}

// ---------------- attention + head -> f32 staging sout ------------------------------
__global__ __launch_bounds__(256) void k_att(const ushort_t* __restrict__ hallB,
                                             const void* __restrict__ Watt,
                                             const void* __restrict__ batt,
                                             const void* __restrict__ Wout,
                                             const void* __restrict__ bout,
                                             float* __restrict__ sout,
                                             const unsigned* __restrict__ dflag) {
    int df = (*dflag) & 1;
    int b = blockIdx.x, tid = threadIdx.x;
    __shared__ float waf[256], lg[128], msk[128], ps[128], enc[256], o3[3], red[1];
    waf[tid] = acc_f(Watt, tid, df);
    __syncthreads();
    int s = tid >> 1, half = tid & 1;
    const ushort_t* hb = hallB + (b * 128 + s) * 256 + half * 128;
    float part = 0.f;
    for (int j = 0; j < 128; ++j) part += b2f(hb[j]) * waf[half * 128 + j];
    part += __shfl_xor(part, 1);
    if (half == 0) lg[s] = part + acc_f(batt, 0, df);
    __syncthreads();
    if (tid < 128) {
        float lv = lg[tid];
        float m = (lv != 0.f) ? 1.f : 0.f;
        msk[tid] = m;
        lg[tid] = lv * m;
    }
    __syncthreads();
    if (tid == 0) {
        float mx = -1e30f;
        for (int i = 0; i < 128; ++i) mx = fmaxf(mx, lg[i]);
        red[0] = mx;
    }
    __syncthreads();
    if (tid < 128) ps[tid] = __expf(lg[tid] - red[0]);
    __syncthreads();
    if (tid == 0) {
        float sm = 0.f;
        for (int i = 0; i < 128; ++i) sm += ps[i];
        red[0] = sm;
    }
    __syncthreads();
    if (tid < 128) ps[tid] = ps[tid] / red[0] * msk[tid];
    __syncthreads();
    if (tid == 0) {
        float sm = 0.f;
        for (int i = 0; i < 128; ++i) sm += ps[i];
        red[0] = sm + 1e-13f;
    }
    __syncthreads();
    if (tid < 128) {
        float p = ps[tid] / red[0];
        ps[tid] = p;
        sout[192 + b * 128 + tid] = p;
    }
    __syncthreads();
    {
        float ej = 0.f;
        for (int ss = 0; ss < 128; ++ss) ej += ps[ss] * b2f(hallB[(b * 128 + ss) * 256 + tid]);
        enc[tid] = ej;
    }
    __syncthreads();
    if (tid < 3) {
        float a = 0.f;
        for (int j = 0; j < 256; ++j) a += enc[j] * acc_f(Wout, tid * 256 + j, df);
        o3[tid] = a + acc_f(bout, tid, df);
    }
    __syncthreads();
    if (tid == 0) {
        float m = fmaxf(o3[0], fmaxf(o3[1], o3[2]));
        float l = logf(__expf(o3[0] - m) + __expf(o3[1] - m) + __expf(o3[2] - m)) + m;
        sout[b * 3 + 0] = o3[0] - l;
        sout[b * 3 + 1] = o3[1] - l;
        sout[b * 3 + 2] = o3[2] - l;
    }
}

// ---------------- finalize: sentinel-or-copy (f32) ----------------------------------
__global__ void k_finalize(const unsigned* __restrict__ flags,
                           const float* __restrict__ sout,
                           float* __restrict__ out, int n) {
    unsigned f = *flags;
    float sval = 0.f;
    int use = 1;
    if (f & 1u) sval = -1024.f;        // NaN/inf in decoded inputs
    else if (f & 2u) sval = -512.f;    // tfeat
    else if (f & 4u) sval = -256.f;    // xw
    else if (f & 8u) sval = -128.f;    // hall
    else if (f & 16u) sval = -64.f;    // staged out
    else use = 0;
    int i = blockIdx.x * 256 + threadIdx.x;
    if (i < n) out[i] = use ? sval : sout[i];
}

extern "C" void kernel_launch(void* const* d_in, const int* in_sizes, int n_in,
                              void* d_out, int out_size, void* d_ws, size_t ws_size,
                              hipStream_t stream) {
    float* out = (float*)d_out;
    static const long long EXP[16] = {8192, 786432, 64, 262144, 15000000, 20000000,
                                      50000, 20000, 512000, 262144, 1024, 1024,
                                      256, 1, 768, 3};
    int ob = (out_size + 255) / 256;
    if (n_in != 16) {
        hipLaunchKernelGGL(k_sentinel, dim3(ob), dim3(256), 0, stream, out, out_size, -8192.f);
        return;
    }
    for (int i = 0; i < 16; ++i) {
        if ((long long)in_sizes[i] != EXP[i]) {
            hipLaunchKernelGGL(k_sentinel, dim3(ob), dim3(256), 0, stream, out, out_size,
                               -(4096.f + 32.f * i));
            return;
        }
    }
    if (out_size != 8384) {
        hipLaunchKernelGGL(k_sentinel, dim3(ob), dim3(256), 0, stream, out, out_size, -2048.f);
        return;
    }

    const void* inputs = d_in[0];
    const void* triples = d_in[1];
    const void* lengths = d_in[2];
    const void* id2 = d_in[3];
    const void* wordE = d_in[4];
    const void* entE = d_in[5];
    const void* relE = d_in[6];
    const void* Went = d_in[7];
    const void* wih = d_in[8];
    const void* whh = d_in[9];
    const void* bih = d_in[10];
    const void* bhh = d_in[11];
    const void* Watt = d_in[12];
    const void* batt = d_in[13];
    const void* Wout = d_in[14];
    const void* bout = d_in[15];
    char* ws = (char*)d_ws;

    constexpr size_t OFF_XW = 0;            // ushort 8192*1024*2 = 16,777,216 (sout f32 overlays after lstm)
    constexpr size_t OFF_TFEAT = 16777216;  // ushort 8192*512*2 = 8,388,608 (hall overlays after gemm)
    constexpr size_t OFF_WIHT = 25165824;   // ushort 512*1024*2 = 1,048,576
    constexpr size_t OFF_WHHP = 26214400;   // uint 128*1024*4 = 524,288
    constexpr size_t OFF_WB = 26738688;     // ushort 112*256*2 = 57,344
    constexpr size_t OFF_FLAGS = 26796032;  // 2x u32 in Wb pad
    constexpr size_t OFF_TRELP = 26804224;  // float 500*112*4 = 224,000 -> end 27,028,224
    constexpr size_t WS_NEEDED = 27028224;

    if (ws_size < WS_NEEDED) {
        hipLaunchKernelGGL(k_sentinel, dim3(ob), dim3(256), 0, stream, out, out_size,
                           -(float)(ws_size >> 20));
        return;
    }

    ushort_t* xwB = (ushort_t*)(ws + OFF_XW);
    float* sout = (float*)(ws + OFF_XW);        // f32 staging overlays xw after k_lstm
    ushort_t* tfeat = (ushort_t*)(ws + OFF_TFEAT);
    ushort_t* hallB = (ushort_t*)(ws + OFF_TFEAT);  // overlays tfeat after k_gemm_xw
    ushort_t* wihT = (ushort_t*)(ws + OFF_WIHT);
    unsigned* whhP = (unsigned*)(ws + OFF_WHHP);
    ushort_t* Wb = (ushort_t*)(ws + OFF_WB);
    unsigned* flags = (unsigned*)(ws + OFF_FLAGS);
    unsigned* dflag = flags + 1;
    float* trelP = (float*)(ws + OFF_TRELP);

    hipLaunchKernelGGL(k_detect, dim3(1), dim3(256), 0, stream, wordE, triples, flags, dflag);
    hipLaunchKernelGGL(k_check_in, dim3(1024), dim3(256), 0, stream, wordE, EXP[4], 1u, dflag, flags);
    hipLaunchKernelGGL(k_check_in, dim3(1024), dim3(256), 0, stream, entE, EXP[5], 1u, dflag, flags);
    hipLaunchKernelGGL(k_check_in, dim3(64), dim3(256), 0, stream, relE, EXP[6], 1u, dflag, flags);
    hipLaunchKernelGGL(k_check_in, dim3(16), dim3(256), 0, stream, Went, EXP[7], 1u, dflag, flags);
    hipLaunchKernelGGL(k_check_in, dim3(256), dim3(256), 0, stream, wih, EXP[8], 1u, dflag, flags);
    hipLaunchKernelGGL(k_check_in, dim3(128), dim3(256), 0, stream, whh, EXP[9], 1u, dflag, flags);
    hipLaunchKernelGGL(k_check_in, dim3(4), dim3(256), 0, stream, bih, EXP[10], 1u, dflag, flags);
    hipLaunchKernelGGL(k_check_in, dim3(4), dim3(256), 0, stream, bhh, EXP[11], 1u, dflag, flags);
    hipLaunchKernelGGL(k_check_in, dim3(1), dim3(256), 0, stream, Watt, EXP[12], 1u, dflag, flags);
    hipLaunchKernelGGL(k_check_in, dim3(1), dim3(256), 0, stream, batt, EXP[13], 1u, dflag, flags);
    hipLaunchKernelGGL(k_check_in, dim3(3), dim3(256), 0, stream, Wout, EXP[14], 1u, dflag, flags);
    hipLaunchKernelGGL(k_check_in, dim3(1), dim3(256), 0, stream, bout, EXP[15], 1u, dflag, flags);

    hipLaunchKernelGGL(k_prep, dim3(2048), dim3(256), 0, stream,
                       Went, wih, whh, relE, Wb, wihT, whhP, trelP, dflag);
    hipLaunchKernelGGL(k_graph, dim3(8192), dim3(128), 0, stream,
                       inputs, triples, id2, wordE, entE, Wb, trelP, tfeat, dflag);
    hipLaunchKernelGGL(k_check_ws, dim3(1024), dim3(256), 0, stream,
                       tfeat, (long long)8192 * 512, 2u, flags);
    hipLaunchKernelGGL(k_gemm_xw, dim3(128, 16), dim3(256), 0, stream,
                       tfeat, wihT, bih, bhh, xwB, dflag);
    hipLaunchKernelGGL(k_check_ws, dim3(1024), dim3(256), 0, stream,
                       xwB, (long long)8192 * 1024, 4u, flags);
    hipLaunchKernelGGL(k_lstm, dim3(32), dim3(1024), 0, stream, xwB, whhP, lengths, hallB, dflag);
    hipLaunchKernelGGL(k_check_ws, dim3(512), dim3(256), 0, stream,
                       hallB, (long long)8192 * 256, 8u, flags);
    hipLaunchKernelGGL(k_att, dim3(64), dim3(256), 0, stream,
                       hallB, Watt, batt, Wout, bout, sout, dflag);
    hipLaunchKernelGGL(k_check_f32, dim3(33), dim3(256), 0, stream,
                       sout, (long long)8384, 16u, flags);
    hipLaunchKernelGGL(k_finalize, dim3(33), dim3(256), 0, stream, flags, sout, out, 8384);
}

// Round 6
// 1471.558 us; speedup vs baseline: 1.6593x; 1.6593x over previous
//
#include <hip/hip_runtime.h>

// RNNSequenceClassifier on MI355X. Inputs/outputs are FLOAT32 (proven R4/R5).
// prep -> graph/t_feat (fused entity-transform MFMA) -> xw GEMM (MFMA, bf16 out)
//   -> prep2 (whh -> MFMA B-fragment order) -> MFMA LSTM scan -> attention/head.
// Workspace: 26,496,000 B (< proven-available 27,028,224 B).

typedef unsigned short ushort_t;
typedef __bf16 bf16x8 __attribute__((ext_vector_type(8)));
typedef float f32x4 __attribute__((ext_vector_type(4)));

#define NENT 200000
#define NVOC 50000
#define NREL 500
#define KPAD 512
#define LDH 264

__device__ __forceinline__ float b2f(ushort_t u) {
    return __uint_as_float(((unsigned)u) << 16);
}
__device__ __forceinline__ ushort_t f2b(float f) {
    unsigned u = __float_as_uint(f);
    unsigned r = (u + 0x7FFFu + ((u >> 16) & 1u)) >> 16;
    return (ushort_t)r;
}
__device__ __forceinline__ float sigm(float x) {
    return __builtin_amdgcn_rcpf(1.f + __expf(-x));
}
__device__ __forceinline__ float tanh_fast(float x) {
    float xx = fminf(fmaxf(x, -15.f), 15.f);
    float t = __expf(2.f * xx);
    return 1.f - 2.f * __builtin_amdgcn_rcpf(t + 1.f);
}
// adaptive int read: int32 (di==0) or int64-low-word (di==1)
__device__ __forceinline__ int iacc(const void* p, long long i, int di) {
    return di ? ((const int*)p)[2 * i] : ((const int*)p)[i];
}

// ---------------- sentinel (f32 out) ------------------------------------------------
__global__ void k_sentinel(float* __restrict__ out, int n, float val) {
    int i = blockIdx.x * 256 + threadIdx.x;
    if (i < n) out[i] = val;
}

// ---------------- tiny int-dtype probe ----------------------------------------------
__global__ void k_det(const int* __restrict__ triples, unsigned* __restrict__ dflag) {
    __shared__ int cnt;
    int tid = threadIdx.x;
    if (tid == 0) cnt = 0;
    __syncthreads();
    int nz = 0;
    for (int i = tid; i < 1500; i += 256)
        if (triples[2 * i + 1] != 0) nz++;
    if (nz) atomicAdd(&cnt, nz);
    __syncthreads();
    if (tid == 0) *dflag = (cnt == 0) ? 2u : 0u;  // bit1: ints are i64
}

// ---------------- prep: Wb[112][256], trelP[500][112], wihT[512][1024] --------------
__global__ void k_prep(const float* __restrict__ Went, const float* __restrict__ wih,
                       const float* __restrict__ relE,
                       ushort_t* __restrict__ Wb, ushort_t* __restrict__ wihT,
                       float* __restrict__ trelP) {
    int i = blockIdx.x * 256 + threadIdx.x;
    int stride = gridDim.x * 256;
    if (i < 112 * 256) {
        int n = i >> 8, k = i & 255;
        float v = 0.f;
        if (n < 100) {
            if (k < 100) v = Went[n * 200 + k];
            else if (k >= 128 && k < 228) v = Went[n * 200 + 100 + (k - 128)];
        }
        Wb[i] = f2b(v);
    }
    for (int j = i; j < 500 * 128; j += stride) {
        int r_ = j >> 7, d = j & 127;
        if (d < 112) trelP[r_ * 112 + d] = (d < 100) ? tanhf(relE[r_ * 100 + d]) : 0.f;
    }
    for (int j = i; j < 512 * 1024; j += stride) {
        int k = j >> 10, n = j & 1023;
        wihT[j] = (k < 500) ? f2b(wih[(long long)n * 500 + k]) : (ushort_t)0;
    }
}

// ---------------- prep2: whhF = w_hh in MFMA B-fragment order (runs after gemm_xw) --
// frag f = nt*8+kt (nt<64, kt<8); lane l, j<8: element B[n=nt*16+(l&15)][k=kt*32+(l>>4)*8+j]
__global__ void k_prep2(const float* __restrict__ whh, ushort_t* __restrict__ whhF) {
    int j = blockIdx.x * 256 + threadIdx.x;  // < 524288
    int f = j >> 9, li = (j >> 3) & 63, jj = j & 7;
    int nt = f >> 3, kt = f & 7;
    int n = nt * 16 + (li & 15);
    int k = kt * 32 + ((li >> 4) << 3) + jj;
    whhF[j] = f2b(whh[n * 256 + k]);
}

// ---------------- graph kernel: one block per (b,s), fused transform MFMA -----------
__global__ __launch_bounds__(128) void k_graph(const void* __restrict__ inputs,
                                               const void* __restrict__ triples,
                                               const void* __restrict__ id2,
                                               const float* __restrict__ wordE,
                                               const float* __restrict__ entE,
                                               const ushort_t* __restrict__ Wb,
                                               const float* __restrict__ trelP,
                                               ushort_t* __restrict__ tfeat,
                                               const unsigned* __restrict__ dflag) {
    int di = ((*dflag) >> 1) & 1;
    int bs = blockIdx.x;
    int tid = threadIdx.x;
    __shared__ __align__(16) ushort_t As[32][256];  // [t][k]: head k<100, tail 128..227
    __shared__ int rids[32];
    __shared__ float e_sm[32];
    __shared__ float alpha[32];
    __shared__ int vflag;
    if (tid == 0) vflag = 0;
    __syncthreads();
    int t = tid >> 2, l4 = tid & 3;
    long long base3 = ((long long)bs * 32 + t) * 3;
    int hid = iacc(triples, base3, di);
    int tl = iacc(triples, base3 + 1, di);
    int rid = iacc(triples, base3 + 2, di);
    hid = min(max(hid, 0), NENT - 1);
    tl = min(max(tl, 0), NENT - 1);
    rid = min(max(rid, 0), NREL - 1);
    if (l4 == 0) {
        rids[t] = rid;
        if (iacc(id2, (long long)bs * 32 + t, di) != -1) vflag = 1;
    }
    for (int k = l4; k < 256; k += 4) {
        float v = 0.f;
        if (k < 100) v = entE[(long long)hid * 100 + k];
        else if (k >= 128 && k < 228) v = entE[(long long)tl * 100 + (k - 128)];
        As[t][k] = f2b(v);
    }
    __syncthreads();
    // GEMM: D[m][n] = sum_k As[m][k]*Wb[n][k], m=32 rows (2 waves x 16), n=112, K=256
    int wave = tid >> 6, lane = tid & 63, m16 = lane & 15, q = lane >> 4;
    f32x4 acc[7];
#pragma unroll
    for (int nt = 0; nt < 7; nt++) acc[nt] = {0.f, 0.f, 0.f, 0.f};
#pragma unroll
    for (int ks = 0; ks < 8; ++ks) {
        bf16x8 af = *reinterpret_cast<const bf16x8*>(&As[wave * 16 + m16][ks * 32 + q * 8]);
#pragma unroll
        for (int nt = 0; nt < 7; ++nt) {
            bf16x8 bf_ = *reinterpret_cast<const bf16x8*>(&Wb[(nt * 16 + m16) * 256 + ks * 32 + q * 8]);
            acc[nt] = __builtin_amdgcn_mfma_f32_16x16x32_bf16(af, bf_, acc[nt], 0, 0, 0);
        }
    }
#pragma unroll
    for (int rr = 0; rr < 4; ++rr) {
        int m = wave * 16 + q * 4 + rr;
        const float* tr = trelP + rids[m] * 112;
        float s = 0.f;
#pragma unroll
        for (int nt = 0; nt < 7; ++nt) s += tanhf(acc[nt][rr]) * tr[nt * 16 + m16];
        s += __shfl_xor(s, 1);
        s += __shfl_xor(s, 2);
        s += __shfl_xor(s, 4);
        s += __shfl_xor(s, 8);
        if (m16 == 0) e_sm[m] = s;
    }
    __syncthreads();
    if (tid < 32) {
        float v = e_sm[tid];
        float mx = v;
        for (int off = 16; off >= 1; off >>= 1) mx = fmaxf(mx, __shfl_xor(mx, off));
        float ex = __expf(v - mx);
        float sm = ex;
        for (int off = 16; off >= 1; off >>= 1) sm += __shfl_xor(sm, off);
        alpha[tid] = ex / sm;
    }
    __syncthreads();
    float scale = vflag ? 1.f : 0.f;
    long long row = (long long)bs * KPAD;
    for (int k = tid; k < 200; k += 128) {
        int kk = (k < 100) ? k : (k + 28);
        float ge = 0.f;
#pragma unroll 8
        for (int tt = 0; tt < 32; ++tt) ge += alpha[tt] * b2f(As[tt][kk]);
        tfeat[row + 300 + k] = f2b(ge * scale);
    }
    int w = iacc(inputs, bs, di);
    w = min(max(w, 0), NVOC - 1);
    for (int j = tid; j < 300; j += 128) tfeat[row + j] = f2b(wordE[(long long)w * 300 + j]);
    if (tid < 12) tfeat[row + 500 + tid] = 0;
}

// ---------------- GEMM: xw = tfeat @ w_ihT + b_ih + b_hh (bf16 out) -----------------
__global__ __launch_bounds__(256) void k_gemm_xw(const ushort_t* __restrict__ A,
                                                 const ushort_t* __restrict__ Bm,
                                                 const float* __restrict__ bih,
                                                 const float* __restrict__ bhh,
                                                 ushort_t* __restrict__ xwB) {
    __shared__ __align__(16) ushort_t As[64 * 32];
    __shared__ __align__(16) ushort_t Bs[64 * 32];
    int tid = threadIdx.x;
    int i0 = blockIdx.x * 64, n0 = blockIdx.y * 64;
    int wave = tid >> 6, lane = tid & 63, m16 = lane & 15, q = lane >> 4;
    f32x4 acc[4];
#pragma unroll
    for (int t = 0; t < 4; t++) acc[t] = {0.f, 0.f, 0.f, 0.f};
    int r = tid >> 2, cq = (tid & 3) * 8;
    int kk = tid >> 3, nn = (tid & 7) * 8;
    for (int kt = 0; kt < 16; ++kt) {
        int k0 = kt * 32;
        {
            const ushort_t* src = A + (i0 + r) * 512 + k0 + cq;
            ushort4 v0 = *(const ushort4*)src;
            ushort4 v1 = *(const ushort4*)(src + 4);
            *(ushort4*)&As[r * 32 + cq] = v0;
            *(ushort4*)&As[r * 32 + cq + 4] = v1;
        }
        {
            const ushort_t* src = Bm + (k0 + kk) * 1024 + n0 + nn;
            ushort4 v0 = *(const ushort4*)(src);
            ushort4 v1 = *(const ushort4*)(src + 4);
            Bs[(nn + 0) * 32 + kk] = v0.x; Bs[(nn + 1) * 32 + kk] = v0.y;
            Bs[(nn + 2) * 32 + kk] = v0.z; Bs[(nn + 3) * 32 + kk] = v0.w;
            Bs[(nn + 4) * 32 + kk] = v1.x; Bs[(nn + 5) * 32 + kk] = v1.y;
            Bs[(nn + 6) * 32 + kk] = v1.z; Bs[(nn + 7) * 32 + kk] = v1.w;
        }
        __syncthreads();
        bf16x8 af = *reinterpret_cast<const bf16x8*>(&As[(wave * 16 + m16) * 32 + q * 8]);
#pragma unroll
        for (int t = 0; t < 4; t++) {
            bf16x8 bf_ = *reinterpret_cast<const bf16x8*>(&Bs[(t * 16 + m16) * 32 + q * 8]);
            acc[t] = __builtin_amdgcn_mfma_f32_16x16x32_bf16(af, bf_, acc[t], 0, 0, 0);
        }
        __syncthreads();
    }
#pragma unroll
    for (int t = 0; t < 4; t++) {
        int n = n0 + t * 16 + m16;
        float bias = bih[n] + bhh[n];
#pragma unroll
        for (int rr = 0; rr < 4; rr++) {
            int i = i0 + wave * 16 + q * 4 + rr;
            xwB[i * 1024 + n] = f2b(acc[t][rr] + bias);
        }
    }
}

// ---------------- LSTM scan: 4 blocks x 1024 threads, 16 batch rows per block -------
// Per step: MFMA gates_hh = h[16,256] @ whh^T (B-frags streamed from L2 in frag order),
// gates -> LDS (bf16, [mg][n][4m]), then 1024 threads combine with prefetched xw.
__global__ __launch_bounds__(1024) void k_lstm(const ushort_t* __restrict__ xwB,
                                               const ushort_t* __restrict__ whhF,
                                               const void* __restrict__ lengths,
                                               ushort_t* __restrict__ hallB,
                                               const unsigned* __restrict__ dflag) {
    int di = ((*dflag) >> 1) & 1;
    int b0 = blockIdx.x * 16;
    int tid = threadIdx.x;
    int wave = tid >> 6, lane = tid & 63;
    int c16 = lane & 15, q = lane >> 4;
    __shared__ __align__(16) ushort_t hsm[16 * LDH];      // h[m][k] bf16
    __shared__ __align__(16) ushort_t gbuf[4 * 1024 * 4]; // gates[mg][n][4m] bf16 (32KB)
    for (int j = tid; j < 16 * LDH; j += 1024) hsm[j] = 0;
    int u = tid & 255, mg = tid >> 8;  // combination mapping: unit u, batch rows mg*4..+3
    int m0 = mg * 4;
    float cst[4] = {0.f, 0.f, 0.f, 0.f};
    int len[4];
#pragma unroll
    for (int r = 0; r < 4; ++r) len[r] = iacc(lengths, b0 + m0 + r, di);
    __syncthreads();
    for (int s = 0; s < 128; ++s) {
        // prefetch xw operands for phase B (independent of phase A -> overlaps MFMA)
        ushort_t xv[4][4];
#pragma unroll
        for (int r = 0; r < 4; ++r) {
            const ushort_t* xr = xwB + ((long long)(b0 + m0 + r) * 128 + s) * 1024 + u;
#pragma unroll
            for (int g = 0; g < 4; ++g) xv[r][g] = xr[g * 256];
        }
        // phase A: wave covers n in [wave*64, wave*64+64)
        bf16x8 afr[8];
#pragma unroll
        for (int kt = 0; kt < 8; ++kt)
            afr[kt] = *reinterpret_cast<const bf16x8*>(&hsm[c16 * LDH + kt * 32 + q * 8]);
#pragma unroll
        for (int i = 0; i < 4; ++i) {
            int ntg = wave * 4 + i;
            const ushort_t* bp = whhF + (((long long)ntg * 8) << 9) + lane * 8;
            f32x4 acc = {0.f, 0.f, 0.f, 0.f};
#pragma unroll
            for (int kt = 0; kt < 8; ++kt) {
                bf16x8 bfr = *reinterpret_cast<const bf16x8*>(bp + (kt << 9));
                acc = __builtin_amdgcn_mfma_f32_16x16x32_bf16(afr[kt], bfr, acc, 0, 0, 0);
            }
            int n = ntg * 16 + c16;
            ushort4 w4;
            w4.x = f2b(acc[0]); w4.y = f2b(acc[1]); w4.z = f2b(acc[2]); w4.w = f2b(acc[3]);
            *(ushort4*)&gbuf[(q * 1024 + n) * 4] = w4;  // mg=q rows m0=q*4..+3
        }
        __syncthreads();
        // phase B
        ushort4 t0 = *(const ushort4*)&gbuf[(mg * 1024 + 0 * 256 + u) * 4];
        ushort4 t1 = *(const ushort4*)&gbuf[(mg * 1024 + 1 * 256 + u) * 4];
        ushort4 t2 = *(const ushort4*)&gbuf[(mg * 1024 + 2 * 256 + u) * 4];
        ushort4 t3 = *(const ushort4*)&gbuf[(mg * 1024 + 3 * 256 + u) * 4];
        ushort_t gi[4] = {t0.x, t0.y, t0.z, t0.w};
        ushort_t gf[4] = {t1.x, t1.y, t1.z, t1.w};
        ushort_t gg[4] = {t2.x, t2.y, t2.z, t2.w};
        ushort_t go[4] = {t3.x, t3.y, t3.z, t3.w};
#pragma unroll
        for (int r = 0; r < 4; ++r) {
            float iv = b2f(gi[r]) + b2f(xv[r][0]);
            float fv = b2f(gf[r]) + b2f(xv[r][1]);
            float gv = b2f(gg[r]) + b2f(xv[r][2]);
            float ov = b2f(go[r]) + b2f(xv[r][3]);
            float c = sigm(fv) * cst[r] + sigm(iv) * tanh_fast(gv);
            float h = sigm(ov) * tanh_fast(c);
            cst[r] = c;
            int m = m0 + r;
            ushort_t hb = f2b(h);
            hsm[m * LDH + u] = hb;
            hallB[((long long)(b0 + m) * 128 + s) * 256 + u] = (s < len[r]) ? hb : (ushort_t)0;
        }
        __syncthreads();
    }
}

// ---------------- attention + classifier head (f32 out) -----------------------------
__global__ __launch_bounds__(256) void k_att(const ushort_t* __restrict__ hallB,
                                             const float* __restrict__ Watt,
                                             const float* __restrict__ batt,
                                             const float* __restrict__ Wout,
                                             const float* __restrict__ bout,
                                             float* __restrict__ out) {
    int b = blockIdx.x, tid = threadIdx.x;
    __shared__ float waf[256], lg[128], msk[128], ps[128], enc[256], o3[3], red[1];
    waf[tid] = Watt[tid];
    __syncthreads();
    int s = tid >> 1, half = tid & 1;
    const ushort_t* hb = hallB + (b * 128 + s) * 256 + half * 128;
    float part = 0.f;
    for (int j = 0; j < 128; ++j) part += b2f(hb[j]) * waf[half * 128 + j];
    part += __shfl_xor(part, 1);
    if (half == 0) lg[s] = part + batt[0];
    __syncthreads();
    if (tid < 128) {
        float lv = lg[tid];
        float m = (lv != 0.f) ? 1.f : 0.f;
        msk[tid] = m;
        lg[tid] = lv * m;
    }
    __syncthreads();
    if (tid == 0) {
        float mx = -1e30f;
        for (int i = 0; i < 128; ++i) mx = fmaxf(mx, lg[i]);
        red[0] = mx;
    }
    __syncthreads();
    if (tid < 128) ps[tid] = __expf(lg[tid] - red[0]);
    __syncthreads();
    if (tid == 0) {
        float sm = 0.f;
        for (int i = 0; i < 128; ++i) sm += ps[i];
        red[0] = sm;
    }
    __syncthreads();
    if (tid < 128) ps[tid] = ps[tid] / red[0] * msk[tid];
    __syncthreads();
    if (tid == 0) {
        float sm = 0.f;
        for (int i = 0; i < 128; ++i) sm += ps[i];
        red[0] = sm + 1e-13f;
    }
    __syncthreads();
    if (tid < 128) {
        float p = ps[tid] / red[0];
        ps[tid] = p;
        out[192 + b * 128 + tid] = p;
    }
    __syncthreads();
    {
        float ej = 0.f;
        for (int ss = 0; ss < 128; ++ss) ej += ps[ss] * b2f(hallB[(b * 128 + ss) * 256 + tid]);
        enc[tid] = ej;
    }
    __syncthreads();
    if (tid < 3) {
        float a = 0.f;
        for (int j = 0; j < 256; ++j) a += enc[j] * Wout[tid * 256 + j];
        o3[tid] = a + bout[tid];
    }
    __syncthreads();
    if (tid == 0) {
        float m = fmaxf(o3[0], fmaxf(o3[1], o3[2]));
        float l = logf(__expf(o3[0] - m) + __expf(o3[1] - m) + __expf(o3[2] - m)) + m;
        out[b * 3 + 0] = o3[0] - l;
        out[b * 3 + 1] = o3[1] - l;
        out[b * 3 + 2] = o3[2] - l;
    }
}

extern "C" void kernel_launch(void* const* d_in, const int* in_sizes, int n_in,
                              void* d_out, int out_size, void* d_ws, size_t ws_size,
                              hipStream_t stream) {
    float* out = (float*)d_out;
    static const long long EXP[16] = {8192, 786432, 64, 262144, 15000000, 20000000,
                                      50000, 20000, 512000, 262144, 1024, 1024,
                                      256, 1, 768, 3};
    int ob = (out_size + 255) / 256;
    if (n_in != 16 || out_size != 8384) {
        hipLaunchKernelGGL(k_sentinel, dim3(ob), dim3(256), 0, stream, out, out_size, -8192.f);
        return;
    }
    for (int i = 0; i < 16; ++i) {
        if ((long long)in_sizes[i] != EXP[i]) {
            hipLaunchKernelGGL(k_sentinel, dim3(ob), dim3(256), 0, stream, out, out_size,
                               -(4096.f + 32.f * i));
            return;
        }
    }

    const void* inputs = d_in[0];
    const void* triples = d_in[1];
    const void* lengths = d_in[2];
    const void* id2 = d_in[3];
    const float* wordE = (const float*)d_in[4];
    const float* entE = (const float*)d_in[5];
    const float* relE = (const float*)d_in[6];
    const float* Went = (const float*)d_in[7];
    const float* wih = (const float*)d_in[8];
    const float* whh = (const float*)d_in[9];
    const float* bih = (const float*)d_in[10];
    const float* bhh = (const float*)d_in[11];
    const float* Watt = (const float*)d_in[12];
    const float* batt = (const float*)d_in[13];
    const float* Wout = (const float*)d_in[14];
    const float* bout = (const float*)d_in[15];
    char* ws = (char*)d_ws;

    // workspace layout — total 26,496,000 B (< proven 27,028,224)
    constexpr size_t OFF_XW = 0;            // ushort 8192*1024*2 = 16,777,216
    constexpr size_t OFF_TFEAT = 16777216;  // ushort 8192*512*2 = 8,388,608 (hallB overlays)
    constexpr size_t OFF_WIHT = 25165824;   // ushort 512*1024*2 = 1,048,576 (whhF overlays after gemm)
    constexpr size_t OFF_WB = 26214400;     // ushort 112*256*2 = 57,344
    constexpr size_t OFF_FLAGS = 26271744;  // u32 dflag (padded to 26,272,000)
    constexpr size_t OFF_TRELP = 26272000;  // float 500*112*4 = 224,000 -> end 26,496,000
    constexpr size_t WS_NEEDED = 26496000;

    if (ws_size < WS_NEEDED) {
        hipLaunchKernelGGL(k_sentinel, dim3(ob), dim3(256), 0, stream, out, out_size,
                           -(float)(ws_size >> 20));
        return;
    }

    ushort_t* xwB = (ushort_t*)(ws + OFF_XW);
    ushort_t* tfeat = (ushort_t*)(ws + OFF_TFEAT);
    ushort_t* hallB = (ushort_t*)(ws + OFF_TFEAT);  // overlays tfeat after k_gemm_xw
    ushort_t* wihT = (ushort_t*)(ws + OFF_WIHT);
    ushort_t* whhF = (ushort_t*)(ws + OFF_WIHT);    // overlays wihT after k_gemm_xw
    ushort_t* Wb = (ushort_t*)(ws + OFF_WB);
    unsigned* dflag = (unsigned*)(ws + OFF_FLAGS);
    float* trelP = (float*)(ws + OFF_TRELP);

    hipLaunchKernelGGL(k_det, dim3(1), dim3(256), 0, stream, (const int*)triples, dflag);
    hipLaunchKernelGGL(k_prep, dim3(2048), dim3(256), 0, stream,
                       Went, wih, relE, Wb, wihT, trelP);
    hipLaunchKernelGGL(k_graph, dim3(8192), dim3(128), 0, stream,
                       inputs, triples, id2, wordE, entE, Wb, trelP, tfeat, dflag);
    hipLaunchKernelGGL(k_gemm_xw, dim3(128, 16), dim3(256), 0, stream,
                       tfeat, wihT, bih, bhh, xwB);
    hipLaunchKernelGGL(k_prep2, dim3(2048), dim3(256), 0, stream, whh, whhF);
    hipLaunchKernelGGL(k_lstm, dim3(4), dim3(1024), 0, stream, xwB, whhF, lengths, hallB, dflag);
    hipLaunchKernelGGL(k_att, dim3(64), dim3(256), 0, stream, hallB, Watt, batt, Wout, bout, out);
}

// Round 7
// 745.440 us; speedup vs baseline: 3.2757x; 1.9741x over previous
//
#include <hip/hip_runtime.h>

// RNNSequenceClassifier on MI355X. Inputs/outputs are FLOAT32 (proven R4/R5).
// prep -> graph/t_feat (fused entity-transform MFMA) -> xw GEMM (MFMA, gate-interleaved
// bf16 out) -> prep2 (whh -> fp8 e4m3 MFMA B-frags, x16 scaled) -> fp8-MFMA LSTM scan
// (weights register-resident: zero weight traffic in the scan loop) -> attention/head.

typedef unsigned short ushort_t;
typedef unsigned char uchar_t;
typedef __bf16 bf16x8 __attribute__((ext_vector_type(8)));
typedef float f32x4 __attribute__((ext_vector_type(4)));

#define NENT 200000
#define NVOC 50000
#define NREL 500
#define KPAD 512
#define LDH8 264  // hsm8 row stride bytes (8-aligned, non-pow2)

__device__ __forceinline__ float b2f(ushort_t u) {
    return __uint_as_float(((unsigned)u) << 16);
}
__device__ __forceinline__ ushort_t f2b(float f) {
    unsigned u = __float_as_uint(f);
    unsigned r = (u + 0x7FFFu + ((u >> 16) & 1u)) >> 16;
    return (ushort_t)r;
}
__device__ __forceinline__ float sigm(float x) {
    return __builtin_amdgcn_rcpf(1.f + __expf(-x));
}
__device__ __forceinline__ float tanh_fast(float x) {
    float xx = fminf(fmaxf(x, -15.f), 15.f);
    float t = __expf(2.f * xx);
    return 1.f - 2.f * __builtin_amdgcn_rcpf(t + 1.f);
}
// float -> OCP e4m3fn (RNE), hand-rolled (no API dependency)
__device__ __forceinline__ uchar_t f2fp8(float x) {
    unsigned s = (__float_as_uint(x) >> 24) & 0x80u;
    float ax = fabsf(x);
    if (ax >= 448.f) return (uchar_t)(s | 0x7E);
    if (ax < 0.015625f) {  // subnormal: q = RNE(ax * 2^9), q==8 rolls into 2^-6 encoding
        float t = ax * 512.f + 12582912.f;  // 1.5*2^23 magic RNE
        unsigned q = __float_as_uint(t) & 0xFFu;
        return (uchar_t)(s | q);
    }
    unsigned au = __float_as_uint(ax);
    unsigned lsb = (au >> 20) & 1u;
    au += 0x0007FFFFu + lsb;  // RNE at mantissa bit 20 (keeps 3 bits)
    int E = ((int)(au >> 23) & 0xFF) - 127 + 7;
    unsigned f3 = (au >> 20) & 7u;
    if (E >= 16) return (uchar_t)(s | 0x7E);
    return (uchar_t)(s | ((unsigned)E << 3) | f3);
}
// adaptive int read: int32 (di==0) or int64-low-word (di==1)
__device__ __forceinline__ int iacc(const void* p, long long i, int di) {
    return di ? ((const int*)p)[2 * i] : ((const int*)p)[i];
}

// ---------------- sentinel (f32 out) ------------------------------------------------
__global__ void k_sentinel(float* __restrict__ out, int n, float val) {
    int i = blockIdx.x * 256 + threadIdx.x;
    if (i < n) out[i] = val;
}

// ---------------- tiny int-dtype probe ----------------------------------------------
__global__ void k_det(const int* __restrict__ triples, unsigned* __restrict__ dflag) {
    __shared__ int cnt;
    int tid = threadIdx.x;
    if (tid == 0) cnt = 0;
    __syncthreads();
    int nz = 0;
    for (int i = tid; i < 1500; i += 256)
        if (triples[2 * i + 1] != 0) nz++;
    if (nz) atomicAdd(&cnt, nz);
    __syncthreads();
    if (tid == 0) *dflag = (cnt == 0) ? 2u : 0u;  // bit1: ints are i64
}

// ---------------- prep: Wb[112][256], trelP[500][112], wihT[512][1024] --------------
__global__ void k_prep(const float* __restrict__ Went, const float* __restrict__ wih,
                       const float* __restrict__ relE,
                       ushort_t* __restrict__ Wb, ushort_t* __restrict__ wihT,
                       float* __restrict__ trelP) {
    int i = blockIdx.x * 256 + threadIdx.x;
    int stride = gridDim.x * 256;
    if (i < 112 * 256) {
        int n = i >> 8, k = i & 255;
        float v = 0.f;
        if (n < 100) {
            if (k < 100) v = Went[n * 200 + k];
            else if (k >= 128 && k < 228) v = Went[n * 200 + 100 + (k - 128)];
        }
        Wb[i] = f2b(v);
    }
    for (int j = i; j < 500 * 128; j += stride) {
        int r_ = j >> 7, d = j & 127;
        if (d < 112) trelP[r_ * 112 + d] = (d < 100) ? tanhf(relE[r_ * 100 + d]) : 0.f;
    }
    for (int j = i; j < 512 * 1024; j += stride) {
        int k = j >> 10, n = j & 1023;
        wihT[j] = (k < 500) ? f2b(wih[(long long)n * 500 + k]) : (ushort_t)0;
    }
}

// ---------------- prep2: whhF8 = 16*w_hh as fp8 e4m3 in MFMA B-fragment order -------
// frag f = ntg*8+kt; lane l, byte j<8: B[n=ntg*16+(l&15)][k=kt*32+(l>>4)*8+j]
__global__ void k_prep2(const float* __restrict__ whh, uchar_t* __restrict__ whhF8) {
    int j = blockIdx.x * 256 + threadIdx.x;  // < 262144
    int f = j >> 9, li = (j >> 3) & 63, jj = j & 7;
    int ntg = f >> 3, kt = f & 7;
    int n = ntg * 16 + (li & 15);
    int k = kt * 32 + ((li >> 4) << 3) + jj;
    whhF8[j] = f2fp8(whh[n * 256 + k] * 16.f);
}

// ---------------- graph kernel: one block per (b,s), fused transform MFMA -----------
__global__ __launch_bounds__(128) void k_graph(const void* __restrict__ inputs,
                                               const void* __restrict__ triples,
                                               const void* __restrict__ id2,
                                               const float* __restrict__ wordE,
                                               const float* __restrict__ entE,
                                               const ushort_t* __restrict__ Wb,
                                               const float* __restrict__ trelP,
                                               ushort_t* __restrict__ tfeat,
                                               const unsigned* __restrict__ dflag) {
    int di = ((*dflag) >> 1) & 1;
    int bs = blockIdx.x;
    int tid = threadIdx.x;
    __shared__ __align__(16) ushort_t As[32][256];  // [t][k]: head k<100, tail 128..227
    __shared__ int rids[32];
    __shared__ float e_sm[32];
    __shared__ float alpha[32];
    __shared__ int vflag;
    if (tid == 0) vflag = 0;
    __syncthreads();
    int t = tid >> 2, l4 = tid & 3;
    long long base3 = ((long long)bs * 32 + t) * 3;
    int hid = iacc(triples, base3, di);
    int tl = iacc(triples, base3 + 1, di);
    int rid = iacc(triples, base3 + 2, di);
    hid = min(max(hid, 0), NENT - 1);
    tl = min(max(tl, 0), NENT - 1);
    rid = min(max(rid, 0), NREL - 1);
    if (l4 == 0) {
        rids[t] = rid;
        if (iacc(id2, (long long)bs * 32 + t, di) != -1) vflag = 1;
    }
    for (int k = l4; k < 256; k += 4) {
        float v = 0.f;
        if (k < 100) v = entE[(long long)hid * 100 + k];
        else if (k >= 128 && k < 228) v = entE[(long long)tl * 100 + (k - 128)];
        As[t][k] = f2b(v);
    }
    __syncthreads();
    int wave = tid >> 6, lane = tid & 63, m16 = lane & 15, q = lane >> 4;
    f32x4 acc[7];
#pragma unroll
    for (int nt = 0; nt < 7; nt++) acc[nt] = {0.f, 0.f, 0.f, 0.f};
#pragma unroll
    for (int ks = 0; ks < 8; ++ks) {
        bf16x8 af = *reinterpret_cast<const bf16x8*>(&As[wave * 16 + m16][ks * 32 + q * 8]);
#pragma unroll
        for (int nt = 0; nt < 7; ++nt) {
            bf16x8 bf_ = *reinterpret_cast<const bf16x8*>(&Wb[(nt * 16 + m16) * 256 + ks * 32 + q * 8]);
            acc[nt] = __builtin_amdgcn_mfma_f32_16x16x32_bf16(af, bf_, acc[nt], 0, 0, 0);
        }
    }
#pragma unroll
    for (int rr = 0; rr < 4; ++rr) {
        int m = wave * 16 + q * 4 + rr;
        const float* tr = trelP + rids[m] * 112;
        float s = 0.f;
#pragma unroll
        for (int nt = 0; nt < 7; ++nt) s += tanhf(acc[nt][rr]) * tr[nt * 16 + m16];
        s += __shfl_xor(s, 1);
        s += __shfl_xor(s, 2);
        s += __shfl_xor(s, 4);
        s += __shfl_xor(s, 8);
        if (m16 == 0) e_sm[m] = s;
    }
    __syncthreads();
    if (tid < 32) {
        float v = e_sm[tid];
        float mx = v;
        for (int off = 16; off >= 1; off >>= 1) mx = fmaxf(mx, __shfl_xor(mx, off));
        float ex = __expf(v - mx);
        float sm = ex;
        for (int off = 16; off >= 1; off >>= 1) sm += __shfl_xor(sm, off);
        alpha[tid] = ex / sm;
    }
    __syncthreads();
    float scale = vflag ? 1.f : 0.f;
    long long row = (long long)bs * KPAD;
    for (int k = tid; k < 200; k += 128) {
        int kk = (k < 100) ? k : (k + 28);
        float ge = 0.f;
#pragma unroll 8
        for (int tt = 0; tt < 32; ++tt) ge += alpha[tt] * b2f(As[tt][kk]);
        tfeat[row + 300 + k] = f2b(ge * scale);
    }
    int w = iacc(inputs, bs, di);
    w = min(max(w, 0), NVOC - 1);
    for (int j = tid; j < 300; j += 128) tfeat[row + j] = f2b(wordE[(long long)w * 300 + j]);
    if (tid < 12) tfeat[row + 500 + tid] = 0;
}

// ---------------- GEMM: xw = tfeat @ w_ihT + b_ih + b_hh (bf16, gate-interleaved) ---
// store layout: xwB[i*1024 + (n&255)*4 + (n>>8)]  (unit-major, 4 gates adjacent)
__global__ __launch_bounds__(256) void k_gemm_xw(const ushort_t* __restrict__ A,
                                                 const ushort_t* __restrict__ Bm,
                                                 const float* __restrict__ bih,
                                                 const float* __restrict__ bhh,
                                                 ushort_t* __restrict__ xwB) {
    __shared__ __align__(16) ushort_t As[64 * 32];
    __shared__ __align__(16) ushort_t Bs[64 * 32];
    int tid = threadIdx.x;
    int i0 = blockIdx.x * 64, n0 = blockIdx.y * 64;
    int wave = tid >> 6, lane = tid & 63, m16 = lane & 15, q = lane >> 4;
    f32x4 acc[4];
#pragma unroll
    for (int t = 0; t < 4; t++) acc[t] = {0.f, 0.f, 0.f, 0.f};
    int r = tid >> 2, cq = (tid & 3) * 8;
    int kk = tid >> 3, nn = (tid & 7) * 8;
    for (int kt = 0; kt < 16; ++kt) {
        int k0 = kt * 32;
        {
            const ushort_t* src = A + (i0 + r) * 512 + k0 + cq;
            ushort4 v0 = *(const ushort4*)src;
            ushort4 v1 = *(const ushort4*)(src + 4);
            *(ushort4*)&As[r * 32 + cq] = v0;
            *(ushort4*)&As[r * 32 + cq + 4] = v1;
        }
        {
            const ushort_t* src = Bm + (k0 + kk) * 1024 + n0 + nn;
            ushort4 v0 = *(const ushort4*)(src);
            ushort4 v1 = *(const ushort4*)(src + 4);
            Bs[(nn + 0) * 32 + kk] = v0.x; Bs[(nn + 1) * 32 + kk] = v0.y;
            Bs[(nn + 2) * 32 + kk] = v0.z; Bs[(nn + 3) * 32 + kk] = v0.w;
            Bs[(nn + 4) * 32 + kk] = v1.x; Bs[(nn + 5) * 32 + kk] = v1.y;
            Bs[(nn + 6) * 32 + kk] = v1.z; Bs[(nn + 7) * 32 + kk] = v1.w;
        }
        __syncthreads();
        bf16x8 af = *reinterpret_cast<const bf16x8*>(&As[(wave * 16 + m16) * 32 + q * 8]);
#pragma unroll
        for (int t = 0; t < 4; t++) {
            bf16x8 bf_ = *reinterpret_cast<const bf16x8*>(&Bs[(t * 16 + m16) * 32 + q * 8]);
            acc[t] = __builtin_amdgcn_mfma_f32_16x16x32_bf16(af, bf_, acc[t], 0, 0, 0);
        }
        __syncthreads();
    }
#pragma unroll
    for (int t = 0; t < 4; t++) {
        int n = n0 + t * 16 + m16;
        float bias = bih[n] + bhh[n];
        int ni = ((n & 255) << 2) + (n >> 8);
#pragma unroll
        for (int rr = 0; rr < 4; rr++) {
            int i = i0 + wave * 16 + q * 4 + rr;
            xwB[i * 1024 + ni] = f2b(acc[t][rr] + bias);
        }
    }
}

// ---------------- LSTM scan: 8 blocks x 512 thr, 8 batch rows/block, fp8 MFMA -------
// w_hh (x16, fp8) register-resident: 8 waves x 8 ntg x 8 kt x 8B = 256 KB/block, zero
// weight traffic in the loop. h stored fp8 (x16) in LDS; acc scaled by 1/256 at use.
__global__ __launch_bounds__(512, 2) void k_lstm(const ushort_t* __restrict__ xwB,
                                                 const uchar_t* __restrict__ whhF8,
                                                 const void* __restrict__ lengths,
                                                 ushort_t* __restrict__ hallB,
                                                 const unsigned* __restrict__ dflag) {
    int di = ((*dflag) >> 1) & 1;
    int b0 = blockIdx.x * 8;
    int tid = threadIdx.x;
    int wave = tid >> 6, lane = tid & 63;
    int c16 = lane & 15, q = lane >> 4;
    __shared__ __align__(16) uchar_t hsm8[16 * LDH8];   // h*16 as fp8, rows 8..15 stay 0
    __shared__ __align__(16) float gbuf[2 * 1024 * 4];  // gates_hh*256 f32 [mg][n][4rows]
    for (int j = tid; j < 16 * LDH8; j += 512) hsm8[j] = 0;
    // load register-resident weight fragments (once)
    long wreg[8][8];
    {
        const uchar_t* wp = whhF8 + (((long long)(wave * 8) * 8) << 9) + lane * 8;
#pragma unroll
        for (int i = 0; i < 8; ++i)
#pragma unroll
            for (int kt = 0; kt < 8; ++kt)
                wreg[i][kt] = *(const long*)(wp + (((i << 3) + kt) << 9));
    }
    int u = tid & 255, mg = tid >> 8;  // phase-B cell: unit u, rows mg*4..mg*4+3
    int m0 = mg * 4;
    float cst[4] = {0.f, 0.f, 0.f, 0.f};
    int len[4];
#pragma unroll
    for (int r = 0; r < 4; ++r) len[r] = iacc(lengths, b0 + m0 + r, di);
    __syncthreads();
    for (int s = 0; s < 128; ++s) {
        // prefetch xw (gate-interleaved): 4 rows x ushort4
        ushort4 xv[4];
#pragma unroll
        for (int r = 0; r < 4; ++r)
            xv[r] = *(const ushort4*)(xwB + ((long long)((b0 + m0 + r) * 128 + s) << 10) + (u << 2));
        // phase A: gates_hh = h @ whh^T via fp8 MFMA, B in registers
        long afr[8];
#pragma unroll
        for (int kt = 0; kt < 8; ++kt)
            afr[kt] = *(const long*)&hsm8[c16 * LDH8 + kt * 32 + q * 8];
#pragma unroll
        for (int i = 0; i < 8; ++i) {
            f32x4 acc = {0.f, 0.f, 0.f, 0.f};
#pragma unroll
            for (int kt = 0; kt < 8; ++kt)
                acc = __builtin_amdgcn_mfma_f32_16x16x32_fp8_fp8(afr[kt], wreg[i][kt], acc, 0, 0, 0);
            if (q < 2) {
                int n = (wave * 8 + i) * 16 + c16;
                *(f32x4*)&gbuf[(q * 1024 + n) * 4] = acc;  // rows q*4+reg
            }
        }
        __syncthreads();
        // phase B: combine, activate, update c/h
        f32x4 gI = *(const f32x4*)&gbuf[(mg * 1024 + u) * 4];
        f32x4 gF = *(const f32x4*)&gbuf[(mg * 1024 + 256 + u) * 4];
        f32x4 gG = *(const f32x4*)&gbuf[(mg * 1024 + 512 + u) * 4];
        f32x4 gO = *(const f32x4*)&gbuf[(mg * 1024 + 768 + u) * 4];
        const float S = 0.00390625f;  // 1/256
#pragma unroll
        for (int r = 0; r < 4; ++r) {
            float iv = b2f((&xv[r].x)[0]) + gI[r] * S;
            float fv = b2f((&xv[r].x)[1]) + gF[r] * S;
            float gv = b2f((&xv[r].x)[2]) + gG[r] * S;
            float ov = b2f((&xv[r].x)[3]) + gO[r] * S;
            float c = sigm(fv) * cst[r] + sigm(iv) * tanh_fast(gv);
            float h = sigm(ov) * tanh_fast(c);
            cst[r] = c;
            int m = m0 + r;
            hsm8[m * LDH8 + u] = f2fp8(h * 16.f);
            hallB[((long long)((b0 + m) * 128 + s) << 8) + u] = (s < len[r]) ? f2b(h) : (ushort_t)0;
        }
        __syncthreads();
    }
}

// ---------------- attention + classifier head (f32 out) -----------------------------
__global__ __launch_bounds__(256) void k_att(const ushort_t* __restrict__ hallB,
                                             const float* __restrict__ Watt,
                                             const float* __restrict__ batt,
                                             const float* __restrict__ Wout,
                                             const float* __restrict__ bout,
                                             float* __restrict__ out) {
    int b = blockIdx.x, tid = threadIdx.x;
    __shared__ float waf[256], lg[128], msk[128], ps[128], enc[256], o3[3], red[1];
    waf[tid] = Watt[tid];
    __syncthreads();
    int s = tid >> 1, half = tid & 1;
    const ushort_t* hb = hallB + (b * 128 + s) * 256 + half * 128;
    float part = 0.f;
    for (int j = 0; j < 128; ++j) part += b2f(hb[j]) * waf[half * 128 + j];
    part += __shfl_xor(part, 1);
    if (half == 0) lg[s] = part + batt[0];
    __syncthreads();
    if (tid < 128) {
        float lv = lg[tid];
        float m = (lv != 0.f) ? 1.f : 0.f;
        msk[tid] = m;
        lg[tid] = lv * m;
    }
    __syncthreads();
    if (tid == 0) {
        float mx = -1e30f;
        for (int i = 0; i < 128; ++i) mx = fmaxf(mx, lg[i]);
        red[0] = mx;
    }
    __syncthreads();
    if (tid < 128) ps[tid] = __expf(lg[tid] - red[0]);
    __syncthreads();
    if (tid == 0) {
        float sm = 0.f;
        for (int i = 0; i < 128; ++i) sm += ps[i];
        red[0] = sm;
    }
    __syncthreads();
    if (tid < 128) ps[tid] = ps[tid] / red[0] * msk[tid];
    __syncthreads();
    if (tid == 0) {
        float sm = 0.f;
        for (int i = 0; i < 128; ++i) sm += ps[i];
        red[0] = sm + 1e-13f;
    }
    __syncthreads();
    if (tid < 128) {
        float p = ps[tid] / red[0];
        ps[tid] = p;
        out[192 + b * 128 + tid] = p;
    }
    __syncthreads();
    {
        float ej = 0.f;
        for (int ss = 0; ss < 128; ++ss) ej += ps[ss] * b2f(hallB[(b * 128 + ss) * 256 + tid]);
        enc[tid] = ej;
    }
    __syncthreads();
    if (tid < 3) {
        float a = 0.f;
        for (int j = 0; j < 256; ++j) a += enc[j] * Wout[tid * 256 + j];
        o3[tid] = a + bout[tid];
    }
    __syncthreads();
    if (tid == 0) {
        float m = fmaxf(o3[0], fmaxf(o3[1], o3[2]));
        float l = logf(__expf(o3[0] - m) + __expf(o3[1] - m) + __expf(o3[2] - m)) + m;
        out[b * 3 + 0] = o3[0] - l;
        out[b * 3 + 1] = o3[1] - l;
        out[b * 3 + 2] = o3[2] - l;
    }
}

extern "C" void kernel_launch(void* const* d_in, const int* in_sizes, int n_in,
                              void* d_out, int out_size, void* d_ws, size_t ws_size,
                              hipStream_t stream) {
    float* out = (float*)d_out;
    static const long long EXP[16] = {8192, 786432, 64, 262144, 15000000, 20000000,
                                      50000, 20000, 512000, 262144, 1024, 1024,
                                      256, 1, 768, 3};
    int ob = (out_size + 255) / 256;
    if (n_in != 16 || out_size != 8384) {
        hipLaunchKernelGGL(k_sentinel, dim3(ob), dim3(256), 0, stream, out, out_size, -8192.f);
        return;
    }
    for (int i = 0; i < 16; ++i) {
        if ((long long)in_sizes[i] != EXP[i]) {
            hipLaunchKernelGGL(k_sentinel, dim3(ob), dim3(256), 0, stream, out, out_size,
                               -(4096.f + 32.f * i));
            return;
        }
    }

    const void* inputs = d_in[0];
    const void* triples = d_in[1];
    const void* lengths = d_in[2];
    const void* id2 = d_in[3];
    const float* wordE = (const float*)d_in[4];
    const float* entE = (const float*)d_in[5];
    const float* relE = (const float*)d_in[6];
    const float* Went = (const float*)d_in[7];
    const float* wih = (const float*)d_in[8];
    const float* whh = (const float*)d_in[9];
    const float* bih = (const float*)d_in[10];
    const float* bhh = (const float*)d_in[11];
    const float* Watt = (const float*)d_in[12];
    const float* batt = (const float*)d_in[13];
    const float* Wout = (const float*)d_in[14];
    const float* bout = (const float*)d_in[15];
    char* ws = (char*)d_ws;

    // workspace layout — total 26,496,000 B (< proven 27,028,224)
    constexpr size_t OFF_XW = 0;            // ushort 8192*1024*2 = 16,777,216
    constexpr size_t OFF_TFEAT = 16777216;  // ushort 8192*512*2 = 8,388,608 (hallB overlays)
    constexpr size_t OFF_WIHT = 25165824;   // ushort 512*1024*2 = 1,048,576 (whhF8 overlays after gemm)
    constexpr size_t OFF_WB = 26214400;     // ushort 112*256*2 = 57,344
    constexpr size_t OFF_FLAGS = 26271744;  // u32 dflag
    constexpr size_t OFF_TRELP = 26272000;  // float 500*112*4 = 224,000 -> end 26,496,000
    constexpr size_t WS_NEEDED = 26496000;

    if (ws_size < WS_NEEDED) {
        hipLaunchKernelGGL(k_sentinel, dim3(ob), dim3(256), 0, stream, out, out_size,
                           -(float)(ws_size >> 20));
        return;
    }

    ushort_t* xwB = (ushort_t*)(ws + OFF_XW);
    ushort_t* tfeat = (ushort_t*)(ws + OFF_TFEAT);
    ushort_t* hallB = (ushort_t*)(ws + OFF_TFEAT);  // overlays tfeat after k_gemm_xw
    ushort_t* wihT = (ushort_t*)(ws + OFF_WIHT);
    uchar_t* whhF8 = (uchar_t*)(ws + OFF_WIHT);     // overlays wihT after k_gemm_xw
    ushort_t* Wb = (ushort_t*)(ws + OFF_WB);
    unsigned* dflag = (unsigned*)(ws + OFF_FLAGS);
    float* trelP = (float*)(ws + OFF_TRELP);

    hipLaunchKernelGGL(k_det, dim3(1), dim3(256), 0, stream, (const int*)triples, dflag);
    hipLaunchKernelGGL(k_prep, dim3(2048), dim3(256), 0, stream,
                       Went, wih, relE, Wb, wihT, trelP);
    hipLaunchKernelGGL(k_graph, dim3(8192), dim3(128), 0, stream,
                       inputs, triples, id2, wordE, entE, Wb, trelP, tfeat, dflag);
    hipLaunchKernelGGL(k_gemm_xw, dim3(128, 16), dim3(256), 0, stream,
                       tfeat, wihT, bih, bhh, xwB);
    hipLaunchKernelGGL(k_prep2, dim3(1024), dim3(256), 0, stream, whh, whhF8);
    hipLaunchKernelGGL(k_lstm, dim3(8), dim3(512), 0, stream, xwB, whhF8, lengths, hallB, dflag);
    hipLaunchKernelGGL(k_att, dim3(64), dim3(256), 0, stream, hallB, Watt, batt, Wout, bout, out);
}